// Round 1
// baseline (775.784 us; speedup 1.0000x reference)
//
#include <hip/hip_runtime.h>
#include <hip/hip_bf16.h>

#define NN 100000
#define NE 1200000
#define DD 64
#define NB_SCAN 391   // ceil(NN/256)

__device__ __forceinline__ float lane_bcast(float v, int k) {
    return __int_as_float(__builtin_amdgcn_readlane(__float_as_int(v), k));
}

// ---- CSR build ----------------------------------------------------------

__global__ void k_zero(int* __restrict__ counts, int* __restrict__ cursor) {
    int i = blockIdx.x * 256 + threadIdx.x;
    if (i < NN) { counts[i] = 0; cursor[i] = 0; }
}

__global__ void k_hist(const int* __restrict__ row, int* __restrict__ counts) {
    int e = blockIdx.x * 256 + threadIdx.x;
    if (e < NE) atomicAdd(&counts[row[e]], 1);
}

__global__ void k_scan1(const int* __restrict__ counts, int* __restrict__ offsets,
                        int* __restrict__ partials) {
    __shared__ int tmp[256];
    int t = threadIdx.x;
    int i = blockIdx.x * 256 + t;
    int v = (i < NN) ? counts[i] : 0;
    tmp[t] = v;
    __syncthreads();
    #pragma unroll
    for (int off = 1; off < 256; off <<= 1) {
        int add = (t >= off) ? tmp[t - off] : 0;
        __syncthreads();
        tmp[t] += add;
        __syncthreads();
    }
    if (i < NN) offsets[i] = tmp[t] - v;          // exclusive
    if (t == 255) partials[blockIdx.x] = tmp[255]; // block total
}

__global__ void k_scan2(int* __restrict__ partials) {
    __shared__ int tmp[512];
    int t = threadIdx.x;
    int v = (t < NB_SCAN) ? partials[t] : 0;
    tmp[t] = v;
    __syncthreads();
    #pragma unroll
    for (int off = 1; off < 512; off <<= 1) {
        int add = (t >= off) ? tmp[t - off] : 0;
        __syncthreads();
        tmp[t] += add;
        __syncthreads();
    }
    if (t < NB_SCAN) partials[t] = tmp[t] - v;     // exclusive
}

__global__ void k_scan3(int* __restrict__ offsets, const int* __restrict__ partials) {
    int i = blockIdx.x * 256 + threadIdx.x;
    if (i < NN) offsets[i] += partials[i >> 8];
}

__global__ void k_scatter(const int* __restrict__ row, const int* __restrict__ col,
                          const float* __restrict__ ew,
                          const int* __restrict__ offsets, int* __restrict__ cursor,
                          int* __restrict__ cs, float* __restrict__ wf) {
    int e = blockIdx.x * 256 + threadIdx.x;
    if (e < NE) {
        int r = row[e];
        int p = offsets[r] + atomicAdd(&cursor[r], 1);
        cs[p] = col[e];
        wf[p] = ew[e];
    }
}

// ---- Fused layer: aggregate + h@Ws + agg@Wn + bias + relu ---------------
// block = 256 threads = 4 waves; each wave handles 4 consecutive nodes.
// lane d computes output column d of its nodes.

__global__ __launch_bounds__(256)
void layer_kernel(const float* __restrict__ h_in, float* __restrict__ h_out,
                  const float* __restrict__ Wself, const float* __restrict__ Wneigh,
                  const float* __restrict__ bias,
                  const int* __restrict__ offsets,
                  const int* __restrict__ cs, const float* __restrict__ wf) {
    __shared__ float sWs[64 * 64];
    __shared__ float sWn[64 * 64];
    __shared__ float sB[64];
    int t = threadIdx.x;
    for (int i = t; i < 64 * 64; i += 256) { sWs[i] = Wself[i]; sWn[i] = Wneigh[i]; }
    if (t < 64) sB[t] = bias[t];
    __syncthreads();

    int lane = t & 63;
    int wave = t >> 6;
    int base = (blockIdx.x * 4 + wave) * 4;

    float hval[4], aval[4];
    #pragma unroll
    for (int m = 0; m < 4; m++) {
        int n = base + m;
        float a = 0.f, hv = 0.f;
        if (n < NN) {
            hv = h_in[n * DD + lane];
            int s = offsets[n];
            int e = (n + 1 < NN) ? offsets[n + 1] : NE;
            #pragma unroll 4
            for (int j = s; j < e; j++) {
                int c = cs[j];
                float w = wf[j];
                a += h_in[c * DD + lane] * w;
            }
        }
        hval[m] = hv;
        aval[m] = a;
    }

    float acc[4];
    #pragma unroll
    for (int m = 0; m < 4; m++) acc[m] = sB[lane];

    #pragma unroll
    for (int k = 0; k < 64; k++) {
        float wsk = sWs[k * 64 + lane];
        float wnk = sWn[k * 64 + lane];
        #pragma unroll
        for (int m = 0; m < 4; m++) {
            acc[m] += lane_bcast(hval[m], k) * wsk + lane_bcast(aval[m], k) * wnk;
        }
    }

    #pragma unroll
    for (int m = 0; m < 4; m++) {
        int n = base + m;
        if (n < NN) h_out[n * DD + lane] = fmaxf(acc[m], 0.f);
    }
}

// ---- launch -------------------------------------------------------------

extern "C" void kernel_launch(void* const* d_in, const int* in_sizes, int n_in,
                              void* d_out, int out_size, void* d_ws, size_t ws_size,
                              hipStream_t stream) {
    const float* x      = (const float*)d_in[0];
    const int*   ei     = (const int*)d_in[1];
    const float* ew     = (const float*)d_in[2];
    const float* selfk  = (const float*)d_in[3];
    const float* neighk = (const float*)d_in[4];
    const float* biases = (const float*)d_in[5];
    float* out = (float*)d_out;

    char* w = (char*)d_ws;
    float* h1      = (float*)w; w += (size_t)NN * DD * sizeof(float);
    float* h2      = (float*)w; w += (size_t)NN * DD * sizeof(float);
    int*   counts  = (int*)w;   w += (size_t)NN * sizeof(int);
    int*   offsets = (int*)w;   w += (size_t)NN * sizeof(int);
    int*   cursor  = (int*)w;   w += (size_t)NN * sizeof(int);
    int*   partials= (int*)w;   w += 512 * sizeof(int);
    int*   cs      = (int*)w;   w += (size_t)NE * sizeof(int);
    float* wf      = (float*)w; w += (size_t)NE * sizeof(float);

    const int* row = ei;
    const int* col = ei + NE;

    k_zero   <<<(NN + 255) / 256, 256, 0, stream>>>(counts, cursor);
    k_hist   <<<(NE + 255) / 256, 256, 0, stream>>>(row, counts);
    k_scan1  <<<NB_SCAN, 256, 0, stream>>>(counts, offsets, partials);
    k_scan2  <<<1, 512, 0, stream>>>(partials);
    k_scan3  <<<NB_SCAN, 256, 0, stream>>>(offsets, partials);
    k_scatter<<<(NE + 255) / 256, 256, 0, stream>>>(row, col, ew, offsets, cursor, cs, wf);

    int lb = (NN + 15) / 16;  // 16 nodes per block
    layer_kernel<<<lb, 256, 0, stream>>>(x,  h1,  selfk,          neighk,          biases,       offsets, cs, wf);
    layer_kernel<<<lb, 256, 0, stream>>>(h1, h2,  selfk + 4096,   neighk + 4096,   biases + 64,  offsets, cs, wf);
    layer_kernel<<<lb, 256, 0, stream>>>(h2, out, selfk + 2*4096, neighk + 2*4096, biases + 128, offsets, cs, wf);
}

// Round 2
// 590.091 us; speedup vs baseline: 1.3147x; 1.3147x over previous
//
#include <hip/hip_runtime.h>

#define NN 100000
#define NE 1200000
#define DD 64
#define NB_SCAN 391   // ceil(NN/256)

__device__ __forceinline__ float lane_bcast(float v, int k) {
    return __int_as_float(__builtin_amdgcn_readlane(__float_as_int(v), k));
}

// ---- CSR build ----------------------------------------------------------

__global__ void k_hist(const int* __restrict__ row, int* __restrict__ counts) {
    int e = blockIdx.x * 256 + threadIdx.x;
    if (e < NE) atomicAdd(&counts[row[e]], 1);
}

__global__ void k_scan1(const int* __restrict__ counts, int* __restrict__ offsets,
                        int* __restrict__ partials) {
    __shared__ int tmp[256];
    int t = threadIdx.x;
    int i = blockIdx.x * 256 + t;
    int v = (i < NN) ? counts[i] : 0;
    tmp[t] = v;
    __syncthreads();
    #pragma unroll
    for (int off = 1; off < 256; off <<= 1) {
        int add = (t >= off) ? tmp[t - off] : 0;
        __syncthreads();
        tmp[t] += add;
        __syncthreads();
    }
    if (i < NN) offsets[i] = tmp[t] - v;           // exclusive
    if (t == 255) partials[blockIdx.x] = tmp[255]; // block total
}

__global__ void k_scan2(int* __restrict__ partials) {
    __shared__ int tmp[512];
    int t = threadIdx.x;
    int v = (t < NB_SCAN) ? partials[t] : 0;
    tmp[t] = v;
    __syncthreads();
    #pragma unroll
    for (int off = 1; off < 512; off <<= 1) {
        int add = (t >= off) ? tmp[t - off] : 0;
        __syncthreads();
        tmp[t] += add;
        __syncthreads();
    }
    if (t < NB_SCAN) partials[t] = tmp[t] - v;     // exclusive
}

__global__ void k_scan3(int* __restrict__ offsets, const int* __restrict__ partials) {
    int i = blockIdx.x * 256 + threadIdx.x;
    if (i < NN) offsets[i] += partials[i >> 8];
    if (i == 0) offsets[NN] = NE;
}

__global__ void k_scatter(const int* __restrict__ row, const int* __restrict__ col,
                          const float* __restrict__ ew,
                          const int* __restrict__ offsets, int* __restrict__ cursor,
                          int2* __restrict__ edges) {
    int e = blockIdx.x * 256 + threadIdx.x;
    if (e < NE) {
        int r = row[e];
        int p = offsets[r] + atomicAdd(&cursor[r], 1);
        edges[p] = make_int2(col[e], __float_as_int(ew[e]));
    }
}

// ---- GEMM: hs = h@Ws + b, y = h@Wn  (8 nodes/wave, readlane broadcast) --

__global__ __launch_bounds__(256)
void gemm_kernel(const float* __restrict__ h, float* __restrict__ hs,
                 float* __restrict__ y,
                 const float* __restrict__ Ws, const float* __restrict__ Wn,
                 const float* __restrict__ bias) {
    __shared__ float sWs[64 * 64];
    __shared__ float sWn[64 * 64];
    __shared__ float sB[64];
    int t = threadIdx.x;
    for (int i = t; i < 64 * 64; i += 256) { sWs[i] = Ws[i]; sWn[i] = Wn[i]; }
    if (t < 64) sB[t] = bias[t];
    __syncthreads();

    int lane = t & 63;
    int wave = t >> 6;
    int base = (blockIdx.x * 4 + wave) * 8;

    float hv[8];
    #pragma unroll
    for (int m = 0; m < 8; m++) {
        int n = base + m;
        hv[m] = (n < NN) ? h[n * DD + lane] : 0.f;
    }

    float as[8], ay[8];
    #pragma unroll
    for (int m = 0; m < 8; m++) { as[m] = sB[lane]; ay[m] = 0.f; }

    #pragma unroll
    for (int k = 0; k < 64; k++) {
        float wsk = sWs[k * 64 + lane];
        float wnk = sWn[k * 64 + lane];
        #pragma unroll
        for (int m = 0; m < 8; m++) {
            float b = lane_bcast(hv[m], k);
            as[m] += b * wsk;
            ay[m] += b * wnk;
        }
    }

    #pragma unroll
    for (int m = 0; m < 8; m++) {
        int n = base + m;
        if (n < NN) {
            hs[n * DD + lane] = as[m];
            y[n * DD + lane]  = ay[m];
        }
    }
}

// ---- Aggregate: out = relu(hs[n] + sum_j w_j * y[col_j]) ---------------
// No LDS, low VGPR -> high occupancy for latency hiding. 2 nodes/wave.

__global__ __launch_bounds__(256)
void agg_kernel(const float* __restrict__ hs, const float* __restrict__ y,
                float* __restrict__ out, const int* __restrict__ offsets,
                const int2* __restrict__ edges) {
    int t = threadIdx.x;
    int lane = t & 63;
    int wave = t >> 6;
    int base = (blockIdx.x * 4 + wave) * 2;

    #pragma unroll
    for (int m = 0; m < 2; m++) {
        int n = base + m;
        if (n < NN) {
            float a = hs[n * DD + lane];
            int s = offsets[n], e = offsets[n + 1];
            #pragma unroll 8
            for (int j = s; j < e; j++) {
                int2 ed = edges[j];
                a += y[ed.x * DD + lane] * __int_as_float(ed.y);
            }
            out[n * DD + lane] = fmaxf(a, 0.f);
        }
    }
}

// ---- launch -------------------------------------------------------------

extern "C" void kernel_launch(void* const* d_in, const int* in_sizes, int n_in,
                              void* d_out, int out_size, void* d_ws, size_t ws_size,
                              hipStream_t stream) {
    const float* x      = (const float*)d_in[0];
    const int*   ei     = (const int*)d_in[1];
    const float* ew     = (const float*)d_in[2];
    const float* selfk  = (const float*)d_in[3];
    const float* neighk = (const float*)d_in[4];
    const float* biases = (const float*)d_in[5];
    float* out = (float*)d_out;

    char* w = (char*)d_ws;
    float* hP      = (float*)w; w += (size_t)NN * DD * sizeof(float);   // layer io
    float* hsQ     = (float*)w; w += (size_t)NN * DD * sizeof(float);   // self path
    float* yR      = (float*)w; w += (size_t)NN * DD * sizeof(float);   // neigh path
    int2*  edges   = (int2*)w;  w += (size_t)NE * sizeof(int2);         // 8B aligned
    int*   counts  = (int*)w;   w += (size_t)NN * sizeof(int);
    int*   cursor  = (int*)w;   w += (size_t)NN * sizeof(int);          // adjacent to counts
    int*   offsets = (int*)w;   w += (size_t)(NN + 1) * sizeof(int);
    int*   partials= (int*)w;   w += 512 * sizeof(int);

    const int* row = ei;
    const int* col = ei + NE;

    hipMemsetAsync(counts, 0, 2 * (size_t)NN * sizeof(int), stream);  // counts+cursor
    k_hist   <<<(NE + 255) / 256, 256, 0, stream>>>(row, counts);
    k_scan1  <<<NB_SCAN, 256, 0, stream>>>(counts, offsets, partials);
    k_scan2  <<<1, 512, 0, stream>>>(partials);
    k_scan3  <<<NB_SCAN, 256, 0, stream>>>(offsets, partials);
    k_scatter<<<(NE + 255) / 256, 256, 0, stream>>>(row, col, ew, offsets, cursor, edges);

    int gemm_blocks = (NN + 31) / 32;   // 8 nodes/wave * 4 waves
    int agg_blocks  = (NN + 7) / 8;     // 2 nodes/wave * 4 waves

    // layer 1: x -> (hsQ, yR) -> hP
    gemm_kernel<<<gemm_blocks, 256, 0, stream>>>(x, hsQ, yR, selfk, neighk, biases);
    agg_kernel <<<agg_blocks, 256, 0, stream>>>(hsQ, yR, hP, offsets, edges);
    // layer 2: hP -> (hsQ, yR) -> hP
    gemm_kernel<<<gemm_blocks, 256, 0, stream>>>(hP, hsQ, yR, selfk + 4096, neighk + 4096, biases + 64);
    agg_kernel <<<agg_blocks, 256, 0, stream>>>(hsQ, yR, hP, offsets, edges);
    // layer 3: hP -> (hsQ, yR) -> out
    gemm_kernel<<<gemm_blocks, 256, 0, stream>>>(hP, hsQ, yR, selfk + 2 * 4096, neighk + 2 * 4096, biases + 128);
    agg_kernel <<<agg_blocks, 256, 0, stream>>>(hsQ, yR, out, offsets, edges);
}

// Round 3
// 533.852 us; speedup vs baseline: 1.4532x; 1.1053x over previous
//
#include <hip/hip_runtime.h>

#define NN 100000
#define NE 1200000
#define DD 64
#define NB_SCAN 391   // ceil(NN/256)

typedef unsigned int uint32;
typedef unsigned short ushort16;

__device__ __forceinline__ float lane_bcast(float v, int k) {
    return __int_as_float(__builtin_amdgcn_readlane(__float_as_int(v), k));
}
__device__ __forceinline__ ushort16 f2bf(float x) {
    uint32 u = __float_as_uint(x);
    u += 0x7FFFu + ((u >> 16) & 1u);   // round-to-nearest-even
    return (ushort16)(u >> 16);
}
__device__ __forceinline__ float bf2f(ushort16 b) {
    return __uint_as_float(((uint32)b) << 16);
}

// ---- CSR build ----------------------------------------------------------

// histogram + per-edge rank in one pass (atomic returns old count = rank)
__global__ void k_hist(const int* __restrict__ row, int* __restrict__ counts,
                       int* __restrict__ rank) {
    int e = blockIdx.x * 256 + threadIdx.x;
    if (e < NE) rank[e] = atomicAdd(&counts[row[e]], 1);
}

__global__ void k_scan1(const int* __restrict__ counts, int* __restrict__ offsets,
                        int* __restrict__ partials) {
    __shared__ int tmp[256];
    int t = threadIdx.x;
    int i = blockIdx.x * 256 + t;
    int v = (i < NN) ? counts[i] : 0;
    tmp[t] = v;
    __syncthreads();
    #pragma unroll
    for (int off = 1; off < 256; off <<= 1) {
        int add = (t >= off) ? tmp[t - off] : 0;
        __syncthreads();
        tmp[t] += add;
        __syncthreads();
    }
    if (i < NN) offsets[i] = tmp[t] - v;           // exclusive
    if (t == 255) partials[blockIdx.x] = tmp[255]; // block total
}

__global__ void k_scan2(int* __restrict__ partials) {
    __shared__ int tmp[512];
    int t = threadIdx.x;
    int v = (t < NB_SCAN) ? partials[t] : 0;
    tmp[t] = v;
    __syncthreads();
    #pragma unroll
    for (int off = 1; off < 512; off <<= 1) {
        int add = (t >= off) ? tmp[t - off] : 0;
        __syncthreads();
        tmp[t] += add;
        __syncthreads();
    }
    if (t < NB_SCAN) partials[t] = tmp[t] - v;     // exclusive
}

__global__ void k_scan3(int* __restrict__ offsets, const int* __restrict__ partials) {
    int i = blockIdx.x * 256 + threadIdx.x;
    if (i < NN) offsets[i] += partials[i >> 8];
    if (i == 0) offsets[NN] = NE;
}

// scatter: no atomic (rank precomputed); 4-byte packed (col<<15 | w_q15)
__global__ void k_scatter(const int* __restrict__ row, const int* __restrict__ col,
                          const float* __restrict__ ew,
                          const int* __restrict__ offsets, const int* __restrict__ rank,
                          uint32* __restrict__ edges) {
    int e = blockIdx.x * 256 + threadIdx.x;
    if (e < NE) {
        int r = row[e];
        int p = offsets[r] + rank[e];
        int wq = (int)(ew[e] * 32767.0f + 0.5f);
        wq = (wq > 32767) ? 32767 : wq;
        edges[p] = ((uint32)col[e] << 15) | (uint32)wq;
    }
}

// ---- GEMM: hs = h@Ws + b, y = h@Wn  (8 nodes/wave, readlane broadcast) --

template <bool IN_BF16>
__global__ __launch_bounds__(256)
void gemm_kernel(const void* __restrict__ h_, ushort16* __restrict__ hs,
                 ushort16* __restrict__ y,
                 const float* __restrict__ Ws, const float* __restrict__ Wn,
                 const float* __restrict__ bias) {
    __shared__ float sWs[64 * 64];
    __shared__ float sWn[64 * 64];
    __shared__ float sB[64];
    int t = threadIdx.x;
    for (int i = t; i < 64 * 64; i += 256) { sWs[i] = Ws[i]; sWn[i] = Wn[i]; }
    if (t < 64) sB[t] = bias[t];
    __syncthreads();

    int lane = t & 63;
    int wave = t >> 6;
    int base = (blockIdx.x * 4 + wave) * 8;

    float hv[8];
    #pragma unroll
    for (int m = 0; m < 8; m++) {
        int n = base + m;
        if (n < NN) {
            hv[m] = IN_BF16 ? bf2f(((const ushort16*)h_)[n * DD + lane])
                            : ((const float*)h_)[n * DD + lane];
        } else hv[m] = 0.f;
    }

    float as[8], ay[8];
    #pragma unroll
    for (int m = 0; m < 8; m++) { as[m] = sB[lane]; ay[m] = 0.f; }

    #pragma unroll
    for (int k = 0; k < 64; k++) {
        float wsk = sWs[k * 64 + lane];
        float wnk = sWn[k * 64 + lane];
        #pragma unroll
        for (int m = 0; m < 8; m++) {
            float b = lane_bcast(hv[m], k);
            as[m] += b * wsk;
            ay[m] += b * wnk;
        }
    }

    #pragma unroll
    for (int m = 0; m < 8; m++) {
        int n = base + m;
        if (n < NN) {
            hs[n * DD + lane] = f2bf(as[m]);
            y[n * DD + lane]  = f2bf(ay[m]);
        }
    }
}

// ---- Aggregate: out = relu(hs[n] + sum_j w_j * y[col_j]) ---------------
// No LDS, low VGPR -> max occupancy for gather latency hiding. 2 nodes/wave.

template <bool OUT_BF16>
__global__ __launch_bounds__(256)
void agg_kernel(const ushort16* __restrict__ hs, const ushort16* __restrict__ y,
                void* __restrict__ out, const int* __restrict__ offsets,
                const uint32* __restrict__ edges) {
    int t = threadIdx.x;
    int lane = t & 63;
    int wave = t >> 6;
    int base = (blockIdx.x * 4 + wave) * 2;

    #pragma unroll
    for (int m = 0; m < 2; m++) {
        int n = base + m;
        if (n < NN) {
            float a = bf2f(hs[n * DD + lane]);
            int s = offsets[n], e = offsets[n + 1];
            #pragma unroll 8
            for (int j = s; j < e; j++) {
                uint32 ed = edges[j];
                int c = (int)(ed >> 15);
                float w = (float)(ed & 32767u) * (1.0f / 32767.0f);
                a += bf2f(y[c * DD + lane]) * w;
            }
            a = fmaxf(a, 0.f);
            if (OUT_BF16) ((ushort16*)out)[n * DD + lane] = f2bf(a);
            else          ((float*)out)[n * DD + lane] = a;
        }
    }
}

// ---- launch -------------------------------------------------------------

extern "C" void kernel_launch(void* const* d_in, const int* in_sizes, int n_in,
                              void* d_out, int out_size, void* d_ws, size_t ws_size,
                              hipStream_t stream) {
    const float* x      = (const float*)d_in[0];
    const int*   ei     = (const int*)d_in[1];
    const float* ew     = (const float*)d_in[2];
    const float* selfk  = (const float*)d_in[3];
    const float* neighk = (const float*)d_in[4];
    const float* biases = (const float*)d_in[5];
    float* out = (float*)d_out;

    char* w = (char*)d_ws;
    ushort16* hP    = (ushort16*)w; w += (size_t)NN * DD * sizeof(ushort16);
    ushort16* hsQ   = (ushort16*)w; w += (size_t)NN * DD * sizeof(ushort16);
    ushort16* yR    = (ushort16*)w; w += (size_t)NN * DD * sizeof(ushort16);
    uint32* edges   = (uint32*)w;   w += (size_t)NE * sizeof(uint32);
    int*    counts  = (int*)w;      w += (size_t)NN * sizeof(int);
    int*    offsets = (int*)w;      w += (size_t)(NN + 1) * sizeof(int);
    int*    rank    = (int*)w;      w += (size_t)NE * sizeof(int);
    int*    partials= (int*)w;      w += 512 * sizeof(int);

    const int* row = ei;
    const int* col = ei + NE;

    hipMemsetAsync(counts, 0, (size_t)NN * sizeof(int), stream);
    k_hist   <<<(NE + 255) / 256, 256, 0, stream>>>(row, counts, rank);
    k_scan1  <<<NB_SCAN, 256, 0, stream>>>(counts, offsets, partials);
    k_scan2  <<<1, 512, 0, stream>>>(partials);
    k_scan3  <<<NB_SCAN, 256, 0, stream>>>(offsets, partials);
    k_scatter<<<(NE + 255) / 256, 256, 0, stream>>>(row, col, ew, offsets, rank, edges);

    int gemm_blocks = (NN + 31) / 32;   // 8 nodes/wave * 4 waves
    int agg_blocks  = (NN + 7) / 8;     // 2 nodes/wave * 4 waves

    // layer 1: x (f32) -> (hsQ, yR) -> hP (bf16)
    gemm_kernel<false><<<gemm_blocks, 256, 0, stream>>>(x, hsQ, yR, selfk, neighk, biases);
    agg_kernel<true>  <<<agg_blocks, 256, 0, stream>>>(hsQ, yR, hP, offsets, edges);
    // layer 2: hP (bf16) -> (hsQ, yR) -> hP (bf16)
    gemm_kernel<true> <<<gemm_blocks, 256, 0, stream>>>(hP, hsQ, yR, selfk + 4096, neighk + 4096, biases + 64);
    agg_kernel<true>  <<<agg_blocks, 256, 0, stream>>>(hsQ, yR, hP, offsets, edges);
    // layer 3: hP (bf16) -> (hsQ, yR) -> out (f32)
    gemm_kernel<true> <<<gemm_blocks, 256, 0, stream>>>(hP, hsQ, yR, selfk + 2 * 4096, neighk + 2 * 4096, biases + 128);
    agg_kernel<false> <<<agg_blocks, 256, 0, stream>>>(hsQ, yR, out, offsets, edges);
}

// Round 4
// 368.728 us; speedup vs baseline: 2.1039x; 1.4478x over previous
//
#include <hip/hip_runtime.h>

#define NN 100000
#define NE 1200000
#define DD 64
#define NB_SCAN 391   // ceil(NN/256)
#define NTILES 3125   // NN/32 exact

typedef unsigned int uint32;
typedef unsigned short ushort16;
typedef __attribute__((ext_vector_type(8))) short short8;    // 8 bf16 (4 VGPR)
typedef __attribute__((ext_vector_type(16))) float f32x16;   // MFMA 32x32 acc

__device__ __forceinline__ ushort16 f2bf(float x) {
    uint32 u = __float_as_uint(x);
    u += 0x7FFFu + ((u >> 16) & 1u);   // round-to-nearest-even
    return (ushort16)(u >> 16);
}
__device__ __forceinline__ float bf2f(ushort16 b) {
    return __uint_as_float(((uint32)b) << 16);
}

// ---- CSR build ----------------------------------------------------------

__global__ void k_hist(const int* __restrict__ row, int* __restrict__ counts,
                       int* __restrict__ rank) {
    int e = blockIdx.x * 256 + threadIdx.x;
    if (e < NE) rank[e] = atomicAdd(&counts[row[e]], 1);
}

__global__ void k_scan1(const int* __restrict__ counts, int* __restrict__ offsets,
                        int* __restrict__ partials) {
    __shared__ int tmp[256];
    int t = threadIdx.x;
    int i = blockIdx.x * 256 + t;
    int v = (i < NN) ? counts[i] : 0;
    tmp[t] = v;
    __syncthreads();
    #pragma unroll
    for (int off = 1; off < 256; off <<= 1) {
        int add = (t >= off) ? tmp[t - off] : 0;
        __syncthreads();
        tmp[t] += add;
        __syncthreads();
    }
    if (i < NN) offsets[i] = tmp[t] - v;           // exclusive
    if (t == 255) partials[blockIdx.x] = tmp[255]; // block total
}

__global__ void k_scan2(int* __restrict__ partials) {
    __shared__ int tmp[512];
    int t = threadIdx.x;
    int v = (t < NB_SCAN) ? partials[t] : 0;
    tmp[t] = v;
    __syncthreads();
    #pragma unroll
    for (int off = 1; off < 512; off <<= 1) {
        int add = (t >= off) ? tmp[t - off] : 0;
        __syncthreads();
        tmp[t] += add;
        __syncthreads();
    }
    if (t < NB_SCAN) partials[t] = tmp[t] - v;     // exclusive
}

__global__ void k_scan3(int* __restrict__ offsets, const int* __restrict__ partials) {
    int i = blockIdx.x * 256 + threadIdx.x;
    if (i < NN) offsets[i] += partials[i >> 8];
    if (i == 0) offsets[NN] = NE;
}

__global__ void k_scatter(const int* __restrict__ row, const int* __restrict__ col,
                          const float* __restrict__ ew,
                          const int* __restrict__ offsets, const int* __restrict__ rank,
                          uint32* __restrict__ edges) {
    int e = blockIdx.x * 256 + threadIdx.x;
    if (e < NE) {
        int r = row[e];
        int p = offsets[r] + rank[e];
        int wq = (int)(ew[e] * 32767.0f + 0.5f);
        wq = (wq > 32767) ? 32767 : wq;
        edges[p] = ((uint32)col[e] << 15) | (uint32)wq;
    }
}

// ---- W pre-pack: lane-ordered bf16 B-fragments for all 3 layers ---------
// frag index within layer: (g*2 + t)*4 + s   (g: 0=self 1=neigh, t: col half,
// s: K-step).  B[k][n]: lane holds n = t*32+(lane&31), k = s*16+(lane>>5)*8+j.

__global__ void k_packW(const float* __restrict__ selfk,
                        const float* __restrict__ neighk,
                        short8* __restrict__ wpack) {
    int tid = blockIdx.x * 256 + threadIdx.x;   // 3 layers * 16 frags * 64 lanes
    if (tid >= 3 * 16 * 64) return;
    int lane  = tid & 63;
    int frag  = (tid >> 6) & 15;
    int layer = tid >> 10;
    int g = frag >> 3;
    int t = (frag >> 2) & 1;
    int s = frag & 3;
    const float* W = (g ? neighk : selfk) + layer * 4096;
    int n = t * 32 + (lane & 31);
    int k0 = s * 16 + (lane >> 5) * 8;
    short8 v;
    #pragma unroll
    for (int j = 0; j < 8; j++) v[j] = (short)f2bf(W[(k0 + j) * 64 + n]);
    wpack[tid] = v;
}

// ---- MFMA GEMM: hs = h@Ws + b, y = h@Wn ---------------------------------
// Each wave: one 32-node x 32-col tile, both matrices (shared A frags).
// t = wid&1 fixed per wave -> W frags hoisted out of the tile loop.

template <bool IN_BF16>
__global__ __launch_bounds__(256)
void gemm_mfma(const void* __restrict__ h_, ushort16* __restrict__ hs,
               ushort16* __restrict__ y,
               const short8* __restrict__ wpack,   // this layer's 16*64 frags
               const float* __restrict__ bias) {
    int lane  = threadIdx.x & 63;
    int wave  = threadIdx.x >> 6;
    int wid   = blockIdx.x * 4 + wave;
    int nwv   = gridDim.x * 4;
    int mrow  = lane & 31;
    int khalf = lane >> 5;
    int t     = wid & 1;

    // W fragments (loop-invariant): coalesced 16B loads, L2-hot
    short8 Wf[2][4];
    #pragma unroll
    for (int g = 0; g < 2; g++)
        #pragma unroll
        for (int s = 0; s < 4; s++)
            Wf[g][s] = wpack[(((g * 2 + t) * 4) + s) * 64 + lane];

    float bval = bias[t * 32 + mrow];

    for (int tile = wid >> 1; tile < NTILES; tile += nwv >> 1) {
        int n0 = tile * 32;

        short8 A[4];
        if (IN_BF16) {
            const short8* hb = (const short8*)h_;
            int base = (n0 + mrow) * 8 + khalf;   // units of 8 bf16
            #pragma unroll
            for (int s = 0; s < 4; s++) A[s] = hb[base + s * 2];
        } else {
            const float* hf = (const float*)h_ + (n0 + mrow) * 64 + khalf * 8;
            #pragma unroll
            for (int s = 0; s < 4; s++) {
                short8 a;
                #pragma unroll
                for (int j = 0; j < 8; j++) a[j] = (short)f2bf(hf[s * 16 + j]);
                A[s] = a;
            }
        }

        f32x16 acc0, acc1;
        #pragma unroll
        for (int r = 0; r < 16; r++) { acc0[r] = 0.f; acc1[r] = 0.f; }

        #pragma unroll
        for (int s = 0; s < 4; s++) {
            acc0 = __builtin_amdgcn_mfma_f32_32x32x16_bf16(A[s], Wf[0][s], acc0, 0, 0, 0);
            acc1 = __builtin_amdgcn_mfma_f32_32x32x16_bf16(A[s], Wf[1][s], acc1, 0, 0, 0);
        }

        int colbase = t * 32 + mrow;
        #pragma unroll
        for (int r = 0; r < 16; r++) {
            int rw = (r & 3) + 8 * (r >> 2) + 4 * khalf;
            int n = n0 + rw;
            hs[n * DD + colbase] = f2bf(acc0[r] + bval);
            y [n * DD + colbase] = f2bf(acc1[r]);
        }
    }
}

// ---- Aggregate: out = relu(hs[n] + sum_j w_j * y[col_j]) ---------------

template <bool OUT_BF16>
__global__ __launch_bounds__(256)
void agg_kernel(const ushort16* __restrict__ hs, const ushort16* __restrict__ y,
                void* __restrict__ out, const int* __restrict__ offsets,
                const uint32* __restrict__ edges) {
    int t = threadIdx.x;
    int lane = t & 63;
    int wave = t >> 6;
    int base = (blockIdx.x * 4 + wave) * 2;

    #pragma unroll
    for (int m = 0; m < 2; m++) {
        int n = base + m;
        if (n < NN) {
            float a = bf2f(hs[n * DD + lane]);
            int s = offsets[n], e = offsets[n + 1];
            #pragma unroll 8
            for (int j = s; j < e; j++) {
                uint32 ed = edges[j];
                int c = (int)(ed >> 15);
                float w = (float)(ed & 32767u) * (1.0f / 32767.0f);
                a += bf2f(y[c * DD + lane]) * w;
            }
            a = fmaxf(a, 0.f);
            if (OUT_BF16) ((ushort16*)out)[n * DD + lane] = f2bf(a);
            else          ((float*)out)[n * DD + lane] = a;
        }
    }
}

// ---- launch -------------------------------------------------------------

extern "C" void kernel_launch(void* const* d_in, const int* in_sizes, int n_in,
                              void* d_out, int out_size, void* d_ws, size_t ws_size,
                              hipStream_t stream) {
    const float* x      = (const float*)d_in[0];
    const int*   ei     = (const int*)d_in[1];
    const float* ew     = (const float*)d_in[2];
    const float* selfk  = (const float*)d_in[3];
    const float* neighk = (const float*)d_in[4];
    const float* biases = (const float*)d_in[5];
    float* out = (float*)d_out;

    char* w = (char*)d_ws;
    ushort16* hP    = (ushort16*)w; w += (size_t)NN * DD * sizeof(ushort16);
    ushort16* hsQ   = (ushort16*)w; w += (size_t)NN * DD * sizeof(ushort16);
    ushort16* yR    = (ushort16*)w; w += (size_t)NN * DD * sizeof(ushort16);
    uint32* edges   = (uint32*)w;   w += (size_t)NE * sizeof(uint32);
    int*    counts  = (int*)w;      w += (size_t)NN * sizeof(int);
    int*    offsets = (int*)w;      w += (size_t)(NN + 1) * sizeof(int);
    int*    rank    = (int*)w;      w += (size_t)NE * sizeof(int);
    int*    partials= (int*)w;      w += 512 * sizeof(int);
    short8* wpack   = (short8*)w;   w += (size_t)3 * 16 * 64 * sizeof(short8);

    const int* row = ei;
    const int* col = ei + NE;

    hipMemsetAsync(counts, 0, (size_t)NN * sizeof(int), stream);
    k_packW  <<<12, 256, 0, stream>>>(selfk, neighk, wpack);
    k_hist   <<<(NE + 255) / 256, 256, 0, stream>>>(row, counts, rank);
    k_scan1  <<<NB_SCAN, 256, 0, stream>>>(counts, offsets, partials);
    k_scan2  <<<1, 512, 0, stream>>>(partials);
    k_scan3  <<<NB_SCAN, 256, 0, stream>>>(offsets, partials);
    k_scatter<<<(NE + 255) / 256, 256, 0, stream>>>(row, col, ew, offsets, rank, edges);

    int gemm_blocks = 782;            // 3128 waves, 6250 wave-jobs -> 2 tiles/wave
    int agg_blocks  = (NN + 7) / 8;   // 2 nodes/wave * 4 waves

    // layer 1: x (f32) -> (hsQ, yR) -> hP (bf16)
    gemm_mfma<false><<<gemm_blocks, 256, 0, stream>>>(x, hsQ, yR, wpack, biases);
    agg_kernel<true><<<agg_blocks, 256, 0, stream>>>(hsQ, yR, hP, offsets, edges);
    // layer 2
    gemm_mfma<true> <<<gemm_blocks, 256, 0, stream>>>(hP, hsQ, yR, wpack + 1024, biases + 64);
    agg_kernel<true><<<agg_blocks, 256, 0, stream>>>(hsQ, yR, hP, offsets, edges);
    // layer 3
    gemm_mfma<true> <<<gemm_blocks, 256, 0, stream>>>(hP, hsQ, yR, wpack + 2048, biases + 128);
    agg_kernel<false><<<agg_blocks, 256, 0, stream>>>(hsQ, yR, out, offsets, edges);
}

// Round 5
// 288.135 us; speedup vs baseline: 2.6924x; 1.2797x over previous
//
#include <hip/hip_runtime.h>

#define NN 100000
#define NE 1200000
#define DD 64
#define NB_SCAN 391   // ceil(NN/256)
#define NTILES 3125   // NN/32 exact

typedef unsigned int uint32;
typedef unsigned short ushort16;
typedef __attribute__((ext_vector_type(8))) short short8;    // 8 bf16 (4 VGPR)
typedef __attribute__((ext_vector_type(16))) float f32x16;   // MFMA 32x32 acc

__device__ __forceinline__ ushort16 f2bf(float x) {
    uint32 u = __float_as_uint(x);
    u += 0x7FFFu + ((u >> 16) & 1u);   // round-to-nearest-even
    return (ushort16)(u >> 16);
}
__device__ __forceinline__ float bf2f(ushort16 b) {
    return __uint_as_float(((uint32)b) << 16);
}
__device__ __forceinline__ float bflo(uint32 u) { return __uint_as_float(u << 16); }
__device__ __forceinline__ float bfhi(uint32 u) { return __uint_as_float(u & 0xFFFF0000u); }
__device__ __forceinline__ uint32 pack2(float a, float b) {
    return (uint32)f2bf(a) | ((uint32)f2bf(b) << 16);
}

// ---- CSR build ----------------------------------------------------------

__global__ void k_hist(const int* __restrict__ row, int* __restrict__ counts,
                       int* __restrict__ rank) {
    int e = blockIdx.x * 256 + threadIdx.x;
    if (e < NE) rank[e] = atomicAdd(&counts[row[e]], 1);
}

__global__ void k_scan1(const int* __restrict__ counts, int* __restrict__ offsets,
                        int* __restrict__ partials) {
    __shared__ int tmp[256];
    int t = threadIdx.x;
    int i = blockIdx.x * 256 + t;
    int v = (i < NN) ? counts[i] : 0;
    tmp[t] = v;
    __syncthreads();
    #pragma unroll
    for (int off = 1; off < 256; off <<= 1) {
        int add = (t >= off) ? tmp[t - off] : 0;
        __syncthreads();
        tmp[t] += add;
        __syncthreads();
    }
    if (i < NN) offsets[i] = tmp[t] - v;           // exclusive
    if (t == 255) partials[blockIdx.x] = tmp[255]; // block total
}

__global__ void k_scan2(int* __restrict__ partials) {
    __shared__ int tmp[512];
    int t = threadIdx.x;
    int v = (t < NB_SCAN) ? partials[t] : 0;
    tmp[t] = v;
    __syncthreads();
    #pragma unroll
    for (int off = 1; off < 512; off <<= 1) {
        int add = (t >= off) ? tmp[t - off] : 0;
        __syncthreads();
        tmp[t] += add;
        __syncthreads();
    }
    if (t < NB_SCAN) partials[t] = tmp[t] - v;     // exclusive
}

__global__ void k_scan3(int* __restrict__ offsets, const int* __restrict__ partials) {
    int i = blockIdx.x * 256 + threadIdx.x;
    if (i < NN) offsets[i] += partials[i >> 8];
    if (i == 0) offsets[NN] = NE;
}

__global__ void k_scatter(const int* __restrict__ row, const int* __restrict__ col,
                          const float* __restrict__ ew,
                          const int* __restrict__ offsets, const int* __restrict__ rank,
                          uint32* __restrict__ edges) {
    int e = blockIdx.x * 256 + threadIdx.x;
    if (e < NE) {
        int r = row[e];
        int p = offsets[r] + rank[e];
        int wq = (int)(ew[e] * 32767.0f + 0.5f);
        wq = (wq > 32767) ? 32767 : wq;
        edges[p] = ((uint32)col[e] << 15) | (uint32)wq;
    }
}

// ---- W pre-pack: lane-ordered bf16 B-fragments for all 3 layers ---------

__global__ void k_packW(const float* __restrict__ selfk,
                        const float* __restrict__ neighk,
                        short8* __restrict__ wpack) {
    int tid = blockIdx.x * 256 + threadIdx.x;   // 3 layers * 16 frags * 64 lanes
    if (tid >= 3 * 16 * 64) return;
    int lane  = tid & 63;
    int frag  = (tid >> 6) & 15;
    int layer = tid >> 10;
    int g = frag >> 3;
    int t = (frag >> 2) & 1;
    int s = frag & 3;
    const float* W = (g ? neighk : selfk) + layer * 4096;
    int n = t * 32 + (lane & 31);
    int k0 = s * 16 + (lane >> 5) * 8;
    short8 v;
    #pragma unroll
    for (int j = 0; j < 8; j++) v[j] = (short)f2bf(W[(k0 + j) * 64 + n]);
    wpack[tid] = v;
}

// ---- MFMA GEMM: hs = h@Ws + b, y = h@Wn ---------------------------------

template <bool IN_BF16>
__global__ __launch_bounds__(256)
void gemm_mfma(const void* __restrict__ h_, ushort16* __restrict__ hs,
               ushort16* __restrict__ y,
               const short8* __restrict__ wpack,   // this layer's 16*64 frags
               const float* __restrict__ bias) {
    int lane  = threadIdx.x & 63;
    int wave  = threadIdx.x >> 6;
    int wid   = blockIdx.x * 4 + wave;
    int nwv   = gridDim.x * 4;
    int mrow  = lane & 31;
    int khalf = lane >> 5;
    int t     = wid & 1;

    short8 Wf[2][4];
    #pragma unroll
    for (int g = 0; g < 2; g++)
        #pragma unroll
        for (int s = 0; s < 4; s++)
            Wf[g][s] = wpack[(((g * 2 + t) * 4) + s) * 64 + lane];

    float bval = bias[t * 32 + mrow];

    for (int tile = wid >> 1; tile < NTILES; tile += nwv >> 1) {
        int n0 = tile * 32;

        short8 A[4];
        if (IN_BF16) {
            const short8* hb = (const short8*)h_;
            int base = (n0 + mrow) * 8 + khalf;   // units of 8 bf16
            #pragma unroll
            for (int s = 0; s < 4; s++) A[s] = hb[base + s * 2];
        } else {
            const float* hf = (const float*)h_ + (n0 + mrow) * 64 + khalf * 8;
            #pragma unroll
            for (int s = 0; s < 4; s++) {
                short8 a;
                #pragma unroll
                for (int j = 0; j < 8; j++) a[j] = (short)f2bf(hf[s * 16 + j]);
                A[s] = a;
            }
        }

        f32x16 acc0, acc1;
        #pragma unroll
        for (int r = 0; r < 16; r++) { acc0[r] = 0.f; acc1[r] = 0.f; }

        #pragma unroll
        for (int s = 0; s < 4; s++) {
            acc0 = __builtin_amdgcn_mfma_f32_32x32x16_bf16(A[s], Wf[0][s], acc0, 0, 0, 0);
            acc1 = __builtin_amdgcn_mfma_f32_32x32x16_bf16(A[s], Wf[1][s], acc1, 0, 0, 0);
        }

        int colbase = t * 32 + mrow;
        #pragma unroll
        for (int r = 0; r < 16; r++) {
            int rw = (r & 3) + 8 * (r >> 2) + 4 * khalf;
            int n = n0 + rw;
            hs[n * DD + colbase] = f2bf(acc0[r] + bval);
            y [n * DD + colbase] = f2bf(acc1[r]);
        }
    }
}

// ---- Aggregate: out = relu(hs[n] + sum_j w_j * y[col_j]) ---------------
// 4 nodes/wave: 16-lane group per node, lane owns 4 features (uint2 gather).
// One gather instruction = 4 edges x 128 B = 512 B.

template <bool OUT_BF16>
__global__ __launch_bounds__(256)
void agg_kernel(const uint2* __restrict__ hs2, const uint2* __restrict__ y2,
                void* __restrict__ out, const int* __restrict__ offsets,
                const uint32* __restrict__ edges) {
    int lane = threadIdx.x & 63;
    int wave = threadIdx.x >> 6;
    int g  = lane >> 4;          // group 0..3 -> node
    int fl = lane & 15;          // features 4*fl .. 4*fl+3
    int n = (blockIdx.x * 4 + wave) * 4 + g;   // 6250*16 == NN exact

    uint2 hv = hs2[n * 16 + fl];
    float a0 = bflo(hv.x), a1 = bfhi(hv.x), a2 = bflo(hv.y), a3 = bfhi(hv.y);

    int s = offsets[n], e = offsets[n + 1];
    #pragma unroll 4
    for (int j = s; j < e; j++) {
        uint32 ed = edges[j];
        int c = (int)(ed >> 15);
        float w = (float)(ed & 32767u) * (1.0f / 32767.0f);
        uint2 yv = y2[c * 16 + fl];
        a0 = fmaf(bflo(yv.x), w, a0);
        a1 = fmaf(bfhi(yv.x), w, a1);
        a2 = fmaf(bflo(yv.y), w, a2);
        a3 = fmaf(bfhi(yv.y), w, a3);
    }
    a0 = fmaxf(a0, 0.f); a1 = fmaxf(a1, 0.f);
    a2 = fmaxf(a2, 0.f); a3 = fmaxf(a3, 0.f);
    if (OUT_BF16) {
        uint2 o; o.x = pack2(a0, a1); o.y = pack2(a2, a3);
        ((uint2*)out)[n * 16 + fl] = o;
    } else {
        ((float4*)out)[n * 16 + fl] = make_float4(a0, a1, a2, a3);
    }
}

// ---- launch -------------------------------------------------------------

extern "C" void kernel_launch(void* const* d_in, const int* in_sizes, int n_in,
                              void* d_out, int out_size, void* d_ws, size_t ws_size,
                              hipStream_t stream) {
    const float* x      = (const float*)d_in[0];
    const int*   ei     = (const int*)d_in[1];
    const float* ew     = (const float*)d_in[2];
    const float* selfk  = (const float*)d_in[3];
    const float* neighk = (const float*)d_in[4];
    const float* biases = (const float*)d_in[5];
    float* out = (float*)d_out;

    char* w = (char*)d_ws;
    ushort16* hP    = (ushort16*)w; w += (size_t)NN * DD * sizeof(ushort16);
    ushort16* hsQ   = (ushort16*)w; w += (size_t)NN * DD * sizeof(ushort16);
    ushort16* yR    = (ushort16*)w; w += (size_t)NN * DD * sizeof(ushort16);
    uint32* edges   = (uint32*)w;   w += (size_t)NE * sizeof(uint32);
    int*    counts  = (int*)w;      w += (size_t)NN * sizeof(int);
    int*    offsets = (int*)w;      w += (size_t)(NN + 1) * sizeof(int);
    int*    rank    = (int*)w;      w += (size_t)NE * sizeof(int);
    int*    partials= (int*)w;      w += 512 * sizeof(int);
    short8* wpack   = (short8*)w;   w += (size_t)3 * 16 * 64 * sizeof(short8);

    const int* row = ei;
    const int* col = ei + NE;

    hipMemsetAsync(counts, 0, (size_t)NN * sizeof(int), stream);
    k_packW  <<<12, 256, 0, stream>>>(selfk, neighk, wpack);
    k_hist   <<<(NE + 255) / 256, 256, 0, stream>>>(row, counts, rank);
    k_scan1  <<<NB_SCAN, 256, 0, stream>>>(counts, offsets, partials);
    k_scan2  <<<1, 512, 0, stream>>>(partials);
    k_scan3  <<<NB_SCAN, 256, 0, stream>>>(offsets, partials);
    k_scatter<<<(NE + 255) / 256, 256, 0, stream>>>(row, col, ew, offsets, rank, edges);

    int gemm_blocks = 782;       // 3128 waves, 6250 wave-jobs -> 2 tiles/wave
    int agg_blocks  = NN / 16;   // 4 nodes/wave * 4 waves = 16 nodes/block, exact

    // layer 1: x (f32) -> (hsQ, yR) -> hP (bf16)
    gemm_mfma<false><<<gemm_blocks, 256, 0, stream>>>(x, hsQ, yR, wpack, biases);
    agg_kernel<true><<<agg_blocks, 256, 0, stream>>>((const uint2*)hsQ, (const uint2*)yR, hP, offsets, edges);
    // layer 2
    gemm_mfma<true> <<<gemm_blocks, 256, 0, stream>>>(hP, hsQ, yR, wpack + 1024, biases + 64);
    agg_kernel<true><<<agg_blocks, 256, 0, stream>>>((const uint2*)hsQ, (const uint2*)yR, hP, offsets, edges);
    // layer 3
    gemm_mfma<true> <<<gemm_blocks, 256, 0, stream>>>(hP, hsQ, yR, wpack + 2048, biases + 128);
    agg_kernel<false><<<agg_blocks, 256, 0, stream>>>((const uint2*)hsQ, (const uint2*)yR, out, offsets, edges);
}